// Round 4
// baseline (504.936 us; speedup 1.0000x reference)
//
#include <hip/hip_runtime.h>
#include <cstdint>
#include <cstddef>

// B=1, S=4096, HIDDEN=2048, HEADS=16, KVH=4, HD=128, CHUNK=1024.
// R4: attention with 128-row Q-tiles (2x register blocking: 0.56 LDS reads per
// MFMA, was 1.06 -> attacks the LDS-pipe bound); fused QKV GEMM (N=3072).
// Frag-ordered LDS throughout; reference-exact non-standard cross-chunk merge.
//
// ws arena (bytes), liveness overlays:
//   part  @ 0          41,943,040   (overlays Xbf@0 16MB + Wt@16MB 12.6MB)
//   QKV   @ 41,943,040 25,165,824   ([4096][3072]: Q | K | V bf16)
//     attn @ 41,943,040 16,777,216  (overlay after partials done)
//   Vt    @ 67,108,864  4,194,304   ([kvh][128][4096] bf16)
//   ml    @ 71,303,168  1,310,720   (fp32 m,l per q-row per partial)
//   Wot   @ 72,613,888  8,388,608
//   total 81,002,496 (~77.3 MB)

typedef unsigned short u16;
typedef unsigned int u32;
typedef float f32x4 __attribute__((ext_vector_type(4)));
typedef __bf16 bf16x8 __attribute__((ext_vector_type(8)));

__device__ __forceinline__ u16 f2bf(float f) {
    union { float f; u32 u; } v; v.f = f;
    u32 u = v.u;
    u += 0x7fffu + ((u >> 16) & 1u);
    return (u16)(u >> 16);
}
__device__ __forceinline__ float bf2f(u16 b) {
    union { u32 u; float f; } v; v.u = ((u32)b) << 16;
    return v.f;
}
__device__ __forceinline__ u16 f2h(float f) {
    union { _Float16 h; u16 u; } v; v.h = (_Float16)f; return v.u;
}
__device__ __forceinline__ float h2f(u16 u) {
    union { u16 u; _Float16 h; } v; v.u = u; return (float)v.h;
}

__device__ __forceinline__ void load16_to_lds(const void* g, void* l) {
    __builtin_amdgcn_global_load_lds((const __attribute__((address_space(1))) u32*)g,
                                     (__attribute__((address_space(3))) u32*)l,
                                     16, 0, 0);
}

#define MFMA16(a, b, c) __builtin_amdgcn_mfma_f32_16x16x32_bf16((a), (b), (c), 0, 0, 0)

// ---------------------------------------------------------------- convert X
__global__ __launch_bounds__(256) void convert_f32_bf16(const float* __restrict__ X,
                                                        u16* __restrict__ Y) {
    const int i = (blockIdx.x * 256 + threadIdx.x) * 4;
    const float4 v = *(const float4*)(X + i);
    union { u16 s[4]; uint2 u; } pk;
    pk.s[0] = f2bf(v.x); pk.s[1] = f2bf(v.y); pk.s[2] = f2bf(v.z); pk.s[3] = f2bf(v.w);
    *(uint2*)(Y + i) = pk.u;
}

// -------------------------------------------- transpose W [K=2048][N] -> Wt [N][2048] bf16
__global__ __launch_bounds__(256) void transpose_w(const float* __restrict__ W,
                                                   u16* __restrict__ Wt, int N) {
    __shared__ float tile[64][65];
    const int n0 = blockIdx.x * 64, k0 = blockIdx.y * 64;
    const int tc = threadIdx.x & 63, tr = threadIdx.x >> 6;
#pragma unroll
    for (int i = 0; i < 64; i += 4)
        tile[tc][tr + i] = W[(size_t)(k0 + tr + i) * N + n0 + tc];
    __syncthreads();
#pragma unroll
    for (int i = 0; i < 64; i += 4)
        Wt[(size_t)(n0 + tr + i) * 2048 + k0 + tc] = f2bf(tile[tr + i][tc]);
}

// ---------------------------------------------------------------- GEMM C = A * Bt^T
// Frag-ordered LDS (conflict-free b128), glds width-16 staging, 128x128 tile.
__device__ __forceinline__ void store_out(float* p, float v) { *p = v; }
__device__ __forceinline__ void store_out(u16* p, float v) { *p = f2bf(v); }

template <typename OutT>
__global__ __launch_bounds__(256) void gemm_bt(const u16* __restrict__ A,
                                               const u16* __restrict__ Bt,
                                               OutT* __restrict__ C,
                                               int M, int N, int K) {
    __shared__ __align__(16) u16 sA[8192];
    __shared__ __align__(16) u16 sB[8192];
    const int t = threadIdx.x;
    const int lane = t & 63, w = t >> 6;
    const int quad = lane >> 4, l15 = lane & 15;
    const int m0 = blockIdx.x << 7, n0 = blockIdx.y << 7;
    const int wr4 = (w >> 1) * 4, wc4 = (w & 1) * 4;
    f32x4 acc[4][4] = {};
    for (int k0 = 0; k0 < K; k0 += 32) {
        __syncthreads();
#pragma unroll
        for (int r = 0; r < 2; ++r) {
            const int f = w * 2 + r;
            load16_to_lds(A + (size_t)(m0 + f * 16 + l15) * K + k0 + quad * 8, sA + f * 512);
            load16_to_lds(Bt + (size_t)(n0 + f * 16 + l15) * K + k0 + quad * 8, sB + f * 512);
        }
        __syncthreads();
        bf16x8 af[4], bb[4];
#pragma unroll
        for (int i = 0; i < 4; ++i)
            af[i] = *(const bf16x8*)(sA + (wr4 + i) * 512 + lane * 8);
#pragma unroll
        for (int j = 0; j < 4; ++j)
            bb[j] = *(const bf16x8*)(sB + (wc4 + j) * 512 + lane * 8);
#pragma unroll
        for (int i = 0; i < 4; ++i)
#pragma unroll
            for (int j = 0; j < 4; ++j)
                acc[i][j] = MFMA16(af[i], bb[j], acc[i][j]);
    }
#pragma unroll
    for (int i = 0; i < 4; ++i)
#pragma unroll
        for (int j = 0; j < 4; ++j) {
            const int row = m0 + (w >> 1) * 64 + i * 16 + quad * 4;
            const int col = n0 + (w & 1) * 64 + j * 16 + l15;
#pragma unroll
            for (int r = 0; r < 4; ++r)
                store_out(C + (size_t)(row + r) * N + col, acc[i][j][r]);
        }
}

// ---------------------------------------------------------------- YaRN RoPE (in place)
// QKV [4096][3072]: Q cols 0..2047 (16 heads), K cols 2048..2559 (4 kv heads).
__global__ __launch_bounds__(256) void rope_kernel(u16* __restrict__ QKV,
                                                   const int* __restrict__ pos_ids) {
    const int idx = blockIdx.x * 256 + threadIdx.x;
    const int NQ = 4096 * 16 * 64;
    u16* p;
    int s, i;
    if (idx < NQ) {
        s = idx >> 10;
        const int hi = idx & 1023;
        const int h = hi >> 6;
        i = hi & 63;
        p = QKV + (size_t)s * 3072 + h * 128 + i;
    } else {
        const int k = idx - NQ;
        if (k >= 4096 * 4 * 64) return;
        s = k >> 8;
        const int hi = k & 255;
        const int h = hi >> 6;
        i = hi & 63;
        p = QKV + (size_t)s * 3072 + 2048 + h * 128 + i;
    }
    const float pf = (float)pos_ids[s];
    const float fi = (float)i;
    const float pos_freq = powf(500000.0f, fi * (1.0f / 64.0f));
    const float inv_ex = 1.0f / pos_freq;
    const float inv_in = inv_ex * (1.0f / 16.0f);
    const float sm = fminf(fmaxf((fi - 18.0f) * (1.0f / 17.0f), 0.0f), 1.0f);
    const float inv = (1.0f - sm) * inv_in + sm * inv_ex;
    const float ph = pf * inv;
    const float MS = 1.2772588722239781f;
    const float cs = cosf(ph) * MS, sn = sinf(ph) * MS;
    const float x1 = bf2f(p[0]), x2 = bf2f(p[64]);
    p[0] = f2bf(x1 * cs - x2 * sn);
    p[64] = f2bf(x2 * cs + x1 * sn);
}

// ---------------------------------------------------------------- V pre-transpose
// QKV [4096][3072] (V = cols 2560+kvh*128+d) -> Vt [kvh][128][4096] bf16
__global__ __launch_bounds__(256) void transpose_v(const u16* __restrict__ QKV,
                                                   u16* __restrict__ Vt) {
    __shared__ u16 tile[64 * 72];
    const int t = threadIdx.x;
    const int k0 = blockIdx.x * 64, d0 = blockIdx.y * 64, kvh = blockIdx.z;
#pragma unroll
    for (int k = 0; k < 4; ++k) {
        const int u = t + k * 256;
        const int key = u >> 4, dg = u & 15;
        const uint2 v = *(const uint2*)(QKV + (size_t)(k0 + key) * 3072 + 2560 + kvh * 128 + d0 + dg * 4);
        *(uint2*)(tile + key * 72 + dg * 4) = v;
    }
    __syncthreads();
#pragma unroll
    for (int k = 0; k < 4; ++k) {
        const int u = t + k * 256;
        const int d = u >> 4, kg = u & 15;
        union { u16 s[4]; uint2 v; } pk;
#pragma unroll
        for (int i = 0; i < 4; ++i) pk.s[i] = tile[(kg * 4 + i) * 72 + d];
        *(uint2*)(Vt + (size_t)(kvh * 128 + d0 + d) * 4096 + k0 + kg * 4) = pk.v;
    }
}

// ---------------------------------------------------------------- attention partials
// grid 1280 (bid = u*16 + h; 80 units/head, longest-first). Block: 128 q rows x one
// 1024-chunk. Wave w owns q-cols [w*32, w*32+32): S^T = K*Q^T with B=Q in regs
// (af[2][4]), 16 K-frag reads -> 32 MFMA; O^T = V^T*P^T, 16 V-frag reads -> 32 MFMA.
// Per-lane softmax state (qrow = l15 within qg). Emits normalized fp16 o-hat
// [d=128][q=128] + fp32 (m,l)/row.
__global__ __launch_bounds__(256, 3) void attn_partial(const u16* __restrict__ QKV,
                                                       const u16* __restrict__ Vt,
                                                       u16* __restrict__ part,
                                                       float* __restrict__ ml) {
    __shared__ __align__(16) u16 sK[8192];   // 16 KB: K frags (Q staging frags 0..15)
    __shared__ __align__(16) u16 sV[8192];   // 16 KB: V^T frags (Q staging frags 16..31)
    __shared__ __align__(16) u16 sP[8192];   // 16 KB: per-wave P^T B-frags (4 x 4KB)

    const int t = threadIdx.x;
    const int lane = t & 63, w = t >> 6;
    const int quad = lane >> 4, l15 = lane & 15;
    const int bid = blockIdx.x;
    const int u = bid >> 4, h = bid & 15, kvh = h >> 2;

    // unit decode (longest-first): u<48 full chunks, u>=48 diagonal by desc length
    int qb, c;
    if (u < 8)       { qb = 8 + u; c = 0; }
    else if (u < 24) { const int r = u - 8;  qb = 16 + (r >> 1); c = r & 1; }
    else if (u < 48) { const int r = u - 24; const int q3 = r / 3; qb = 24 + q3; c = r - q3 * 3; }
    else             { const int r = u - 48; const int k = r >> 2; const int g0 = r & 3;
                       qb = g0 * 8 + (7 - k); c = g0; }
    const int g = qb >> 3;
    const int q0 = qb << 7, kv0 = c << 10;
    const int jmax = (c == g) ? (2 * (qb & 7) + 2) : 16;

    // stage Q into 32 frags across sK+sV, then into registers af[qg][kc]
    {
        u16* dst0 = (w < 2) ? (u16*)sK : (u16*)sV;
        const int fbase = (w & 1) * 8;
#pragma unroll
        for (int idx = 0; idx < 8; ++idx) {
            const int qg = idx >> 2, kc = idx & 3;
            load16_to_lds(QKV + (size_t)(q0 + w * 32 + qg * 16 + l15) * 3072 + h * 128 + kc * 32 + quad * 8,
                          dst0 + (fbase + idx) * 512);
        }
    }
    __syncthreads();
    bf16x8 af[2][4];
    {
        const u16* src0 = (w < 2) ? (const u16*)sK : (const u16*)sV;
        const int fbase = (w & 1) * 8;
#pragma unroll
        for (int qg = 0; qg < 2; ++qg)
#pragma unroll
            for (int kc = 0; kc < 4; ++kc)
                af[qg][kc] = *(const bf16x8*)(src0 + (fbase + qg * 4 + kc) * 512 + lane * 8);
    }

    float m_c[2] = {-1e30f, -1e30f}, l_c[2] = {0.0f, 0.0f};
    f32x4 o_c[8][2] = {};
    const float SCALE = 0.08838834764831845f;  // 128^-0.5

    for (int j = 0; j < jmax; ++j) {
        const int kt0 = kv0 + (j << 6);
        __syncthreads();   // prior tile consumed (Q-frag reads on first iter)
        // stage K: wave w -> frags (kg=w, kc=0..3); V^T: frags (dt=w*2+(r>>1), ks=r&1)
        {
            const u16* gk = QKV + (size_t)(kt0 + w * 16 + l15) * 3072 + 2048 + kvh * 128 + quad * 8;
#pragma unroll
            for (int kc = 0; kc < 4; ++kc)
                load16_to_lds(gk + kc * 32, sK + (w * 4 + kc) * 512);
#pragma unroll
            for (int r = 0; r < 4; ++r) {
                const int dt = w * 2 + (r >> 1), ks = r & 1;
                load16_to_lds(Vt + (size_t)(kvh * 128 + dt * 16 + l15) * 4096 + kt0 + ks * 32 + quad * 8,
                              sV + (dt * 2 + ks) * 512);
            }
        }
        __syncthreads();

        // S^T = K * Q^T : 16 K-frag reads, 32 MFMA (reuse across qg)
        f32x4 sacc[4][2] = {};
#pragma unroll
        for (int j4 = 0; j4 < 4; ++j4)
#pragma unroll
            for (int kc = 0; kc < 4; ++kc) {
                const bf16x8 kf = *(const bf16x8*)(sK + (j4 * 4 + kc) * 512 + lane * 8);
                sacc[j4][0] = MFMA16(kf, af[0][kc], sacc[j4][0]);
                sacc[j4][1] = MFMA16(kf, af[1][kc], sacc[j4][1]);
            }

        // scale + causal mask (only last two tiles of diagonal chunk)
        const bool diag = (c == g) && ((j >> 1) == (qb & 7));
        if (diag) {
#pragma unroll
            for (int j4 = 0; j4 < 4; ++j4)
#pragma unroll
                for (int qg = 0; qg < 2; ++qg) {
                    const int qrow = q0 + w * 32 + qg * 16 + l15;
#pragma unroll
                    for (int r = 0; r < 4; ++r) {
                        const int key = kt0 + j4 * 16 + quad * 4 + r;
                        sacc[j4][qg][r] = (key > qrow) ? -1e30f : sacc[j4][qg][r] * SCALE;
                    }
                }
        } else {
#pragma unroll
            for (int j4 = 0; j4 < 4; ++j4)
#pragma unroll
                for (int qg = 0; qg < 2; ++qg)
#pragma unroll
                    for (int r = 0; r < 4; ++r)
                        sacc[j4][qg][r] *= SCALE;
        }

        // online softmax per qg (qrow = l15 lane state; reduce across quads)
#pragma unroll
        for (int qg = 0; qg < 2; ++qg) {
            float mx = -1e30f;
#pragma unroll
            for (int j4 = 0; j4 < 4; ++j4)
#pragma unroll
                for (int r = 0; r < 4; ++r) mx = fmaxf(mx, sacc[j4][qg][r]);
            mx = fmaxf(mx, __shfl_xor(mx, 16, 64));
            mx = fmaxf(mx, __shfl_xor(mx, 32, 64));
            const float mn = fmaxf(m_c[qg], mx);
            const float alpha = __expf(m_c[qg] - mn);
            float ps = 0.0f;
#pragma unroll
            for (int j4 = 0; j4 < 4; ++j4)
#pragma unroll
                for (int r = 0; r < 4; ++r) {
                    const float pe = __expf(sacc[j4][qg][r] - mn);
                    sacc[j4][qg][r] = pe;
                    ps += pe;
                }
            ps += __shfl_xor(ps, 16, 64);
            ps += __shfl_xor(ps, 32, 64);
            l_c[qg] = l_c[qg] * alpha + ps;
            m_c[qg] = mn;
#pragma unroll
            for (int dt = 0; dt < 8; ++dt) o_c[dt][qg] *= alpha;
        }

        // pack P^T into per-wave B-frags: frag (qg*2+ks), pos (quad'=jj*2+(quad>>1),
        // j=(quad&1)*4+r), written as u32 pairs
#pragma unroll
        for (int ks = 0; ks < 2; ++ks)
#pragma unroll
            for (int jj = 0; jj < 2; ++jj) {
                const int j4 = ks * 2 + jj;
                const int quadp = jj * 2 + (quad >> 1);
#pragma unroll
                for (int qg = 0; qg < 2; ++qg)
#pragma unroll
                    for (int pr = 0; pr < 2; ++pr) {
                        const int r = pr * 2;
                        const int jje = (quad & 1) * 4 + r;
                        const u32 pk = ((u32)f2bf(sacc[j4][qg][r + 1]) << 16) | f2bf(sacc[j4][qg][r]);
                        *(u32*)(sP + w * 2048 + (qg * 2 + ks) * 512 + (quadp * 16 + l15) * 8 + jje) = pk;
                    }
            }

        // O^T += V^T * P^T : 16 V-frag reads, 32 MFMA (reuse across qg)
#pragma unroll
        for (int ks = 0; ks < 2; ++ks) {
            const bf16x8 pf0 = *(const bf16x8*)(sP + w * 2048 + (0 * 2 + ks) * 512 + lane * 8);
            const bf16x8 pf1 = *(const bf16x8*)(sP + w * 2048 + (1 * 2 + ks) * 512 + lane * 8);
#pragma unroll
            for (int dt = 0; dt < 8; ++dt) {
                const bf16x8 vf = *(const bf16x8*)(sV + (dt * 2 + ks) * 512 + lane * 8);
                o_c[dt][0] = MFMA16(vf, pf0, o_c[dt][0]);
                o_c[dt][1] = MFMA16(vf, pf1, o_c[dt][1]);
            }
        }
    }

    // epilogue: part [bid][d=128][q=128] fp16, ml [bid][q=128][2] fp32
#pragma unroll
    for (int qg = 0; qg < 2; ++qg) {
        const float invl = 1.0f / l_c[qg];
        const int q = w * 32 + qg * 16 + l15;
#pragma unroll
        for (int dt = 0; dt < 8; ++dt)
#pragma unroll
            for (int r = 0; r < 4; ++r)
                part[(size_t)bid * 16384 + (dt * 16 + quad * 4 + r) * 128 + q] =
                    f2h(o_c[dt][qg][r] * invl);
        if (quad == 0) {
            ml[(size_t)bid * 256 + q * 2] = m_c[qg];
            ml[(size_t)bid * 256 + q * 2 + 1] = l_c[qg];
        }
    }
}

// ---------------------------------------------------------------- merge partials
// grid (512, 2): x = qb*16+h, y = d-half. Thread: qrow = t&127, dgrp = t>>7 -> 32 d.
// Reference merge IN CHUNK ORDER: d = a + sE + 1e-10; o = o*(l_g/d) + ohat*sE/d.
__global__ __launch_bounds__(256) void attn_merge(const u16* __restrict__ part,
                                                  const float* __restrict__ ml,
                                                  u16* __restrict__ attn) {
    const int b = blockIdx.x;
    const int qb = b >> 4, h = b & 15;
    const int g = qb >> 3;
    const int t = threadIdx.x;
    const int qrow = t & 127;
    const int d0 = blockIdx.y * 64 + (t >> 7) * 32;

    float o[32];
#pragma unroll
    for (int i = 0; i < 32; ++i) o[i] = 0.0f;
    float m_g = -1e30f, l_g = 0.0f;

    for (int c = 0; c <= g; ++c) {
        int u;
        if (c == g)      u = 48 + (7 - (qb & 7)) * 4 + g;
        else if (g == 1) u = qb - 8;
        else if (g == 2) u = 8 + (qb - 16) * 2 + c;
        else             u = 24 + (qb - 24) * 3 + c;
        const int tile = u * 16 + h;
        const float m_c = ml[(size_t)tile * 256 + qrow * 2];
        const float l_c = ml[(size_t)tile * 256 + qrow * 2 + 1];
        const float mn = fmaxf(m_g, m_c);
        const float a = l_g * __expf(m_g - mn);
        const float eC = __expf(m_c - mn);
        const float sE = l_c * eC;
        const float d = a + sE + 1e-10f;
        const float f_old = l_g / d;
        const float f_new = sE / d;
#pragma unroll
        for (int i = 0; i < 32; ++i) {
            const float v = h2f(part[(size_t)tile * 16384 + (d0 + i) * 128 + qrow]);
            o[i] = o[i] * f_old + v * f_new;
        }
        l_g = a + sE;
        m_g = mn;
    }

    u16* dst = attn + (size_t)(qb * 128 + qrow) * 2048 + h * 128 + d0;
#pragma unroll
    for (int kq = 0; kq < 4; ++kq) {
        union { u16 s[8]; uint4 v; } pk;
#pragma unroll
        for (int i = 0; i < 8; ++i) pk.s[i] = f2bf(o[kq * 8 + i]);
        *(uint4*)(dst + kq * 8) = pk.v;
    }
}

// ---------------------------------------------------------------- launch
extern "C" void kernel_launch(void* const* d_in, const int* in_sizes, int n_in,
                              void* d_out, int out_size, void* d_ws, size_t ws_size,
                              hipStream_t stream) {
    const float* X  = (const float*)d_in[0];
    const int* pos  = (const int*)d_in[1];
    const float* Wq = (const float*)d_in[2];
    const float* Wk = (const float*)d_in[3];
    const float* Wv = (const float*)d_in[4];
    const float* Wo = (const float*)d_in[5];
    float* out = (float*)d_out;
    char* ws = (char*)d_ws;

    u16*   part = (u16*)(ws);
    u16*   Xbf  = (u16*)(ws);                      // overlay (dead before part)
    u16*   Wt   = (u16*)(ws + 16777216);           // [3072][2048] overlay
    u16*   QKV  = (u16*)(ws + 41943040);
    u16*   attn = (u16*)(ws + 41943040);           // overlay QKV (dead after partials)
    u16*   Vt   = (u16*)(ws + 67108864);
    float* ml   = (float*)(ws + 71303168);
    u16*   Wot  = (u16*)(ws + 72613888);

    convert_f32_bf16<<<8192, 256, 0, stream>>>(X, Xbf);
    transpose_w<<<dim3(32, 32), 256, 0, stream>>>(Wq, Wt, 2048);
    transpose_w<<<dim3(8, 32), 256, 0, stream>>>(Wk, Wt + (size_t)2048 * 2048, 512);
    transpose_w<<<dim3(8, 32), 256, 0, stream>>>(Wv, Wt + (size_t)2560 * 2048, 512);
    transpose_w<<<dim3(32, 32), 256, 0, stream>>>(Wo, Wot, 2048);

    gemm_bt<u16><<<dim3(32, 24), 256, 0, stream>>>(Xbf, Wt, QKV, 4096, 3072, 2048);

    rope_kernel<<<20480, 256, 0, stream>>>(QKV, pos);
    transpose_v<<<dim3(64, 2, 4), 256, 0, stream>>>(QKV, Vt);

    attn_partial<<<1280, 256, 0, stream>>>(QKV, Vt, part, ml);
    attn_merge<<<dim3(512, 2), 256, 0, stream>>>(part, ml, attn);

    gemm_bt<float><<<dim3(32, 16), 256, 0, stream>>>(attn, Wot, out, 4096, 2048, 2048);
}

// Round 5
// 459.244 us; speedup vs baseline: 1.0995x; 1.0995x over previous
//
#include <hip/hip_runtime.h>
#include <cstdint>
#include <cstddef>

// B=1, S=4096, HIDDEN=2048, HEADS=16, KVH=4, HD=128, CHUNK=1024.
// R5: R4 structure with the spill fixed — attn_partial at __launch_bounds__(256,2)
// (register budget 256/wave; R4's (256,3) budget of ~170 forced ~65 f32/thread of
// scratch spill: WRITE_SIZE 42->128 MB). GEMM moves to BK=64 (32 MFMA per barrier
// pair, LDS 32 KB fully used, 5 blocks/CU).
//
// ws arena (bytes), liveness overlays:
//   part  @ 0          41,943,040   (overlays Xbf@0 16MB + Wt@16MB 12.6MB)
//   QKV   @ 41,943,040 25,165,824   ([4096][3072]: Q | K | V bf16)
//     attn @ 41,943,040 16,777,216  (overlay after partials done)
//   Vt    @ 67,108,864  4,194,304   ([kvh][128][4096] bf16)
//   ml    @ 71,303,168  1,310,720   (fp32 m,l per q-row per partial)
//   Wot   @ 72,613,888  8,388,608
//   total 81,002,496 (~77.3 MB)

typedef unsigned short u16;
typedef unsigned int u32;
typedef float f32x4 __attribute__((ext_vector_type(4)));
typedef __bf16 bf16x8 __attribute__((ext_vector_type(8)));

__device__ __forceinline__ u16 f2bf(float f) {
    union { float f; u32 u; } v; v.f = f;
    u32 u = v.u;
    u += 0x7fffu + ((u >> 16) & 1u);
    return (u16)(u >> 16);
}
__device__ __forceinline__ float bf2f(u16 b) {
    union { u32 u; float f; } v; v.u = ((u32)b) << 16;
    return v.f;
}
__device__ __forceinline__ u16 f2h(float f) {
    union { _Float16 h; u16 u; } v; v.h = (_Float16)f; return v.u;
}
__device__ __forceinline__ float h2f(u16 u) {
    union { u16 u; _Float16 h; } v; v.u = u; return (float)v.h;
}

__device__ __forceinline__ void load16_to_lds(const void* g, void* l) {
    __builtin_amdgcn_global_load_lds((const __attribute__((address_space(1))) u32*)g,
                                     (__attribute__((address_space(3))) u32*)l,
                                     16, 0, 0);
}

#define MFMA16(a, b, c) __builtin_amdgcn_mfma_f32_16x16x32_bf16((a), (b), (c), 0, 0, 0)

// ---------------------------------------------------------------- convert X
__global__ __launch_bounds__(256) void convert_f32_bf16(const float* __restrict__ X,
                                                        u16* __restrict__ Y) {
    const int i = (blockIdx.x * 256 + threadIdx.x) * 4;
    const float4 v = *(const float4*)(X + i);
    union { u16 s[4]; uint2 u; } pk;
    pk.s[0] = f2bf(v.x); pk.s[1] = f2bf(v.y); pk.s[2] = f2bf(v.z); pk.s[3] = f2bf(v.w);
    *(uint2*)(Y + i) = pk.u;
}

// -------------------------------------------- transpose W [K=2048][N] -> Wt [N][2048] bf16
__global__ __launch_bounds__(256) void transpose_w(const float* __restrict__ W,
                                                   u16* __restrict__ Wt, int N) {
    __shared__ float tile[64][65];
    const int n0 = blockIdx.x * 64, k0 = blockIdx.y * 64;
    const int tc = threadIdx.x & 63, tr = threadIdx.x >> 6;
#pragma unroll
    for (int i = 0; i < 64; i += 4)
        tile[tc][tr + i] = W[(size_t)(k0 + tr + i) * N + n0 + tc];
    __syncthreads();
#pragma unroll
    for (int i = 0; i < 64; i += 4)
        Wt[(size_t)(n0 + tr + i) * 2048 + k0 + tc] = f2bf(tile[tr + i][tc]);
}

// ---------------------------------------------------------------- GEMM C = A * Bt^T
// BK=64: 16 frags x 1KB per matrix (32 KB LDS total), 32 MFMA per barrier pair.
// Frag-ordered LDS -> conflict-free ds_read_b128; glds width-16 staging.
__device__ __forceinline__ void store_out(float* p, float v) { *p = v; }
__device__ __forceinline__ void store_out(u16* p, float v) { *p = f2bf(v); }

template <typename OutT>
__global__ __launch_bounds__(256) void gemm_bt(const u16* __restrict__ A,
                                               const u16* __restrict__ Bt,
                                               OutT* __restrict__ C,
                                               int M, int N, int K) {
    __shared__ __align__(16) u16 sA[8192];   // 16 frags (row-group f, k-slice kc): f*2+kc
    __shared__ __align__(16) u16 sB[8192];
    const int t = threadIdx.x;
    const int lane = t & 63, w = t >> 6;
    const int quad = lane >> 4, l15 = lane & 15;
    const int m0 = blockIdx.x << 7, n0 = blockIdx.y << 7;
    const int wr4 = (w >> 1) * 4, wc4 = (w & 1) * 4;
    f32x4 acc[4][4] = {};
    for (int k0 = 0; k0 < K; k0 += 64) {
        __syncthreads();
#pragma unroll
        for (int r = 0; r < 2; ++r) {
            const int f = w * 2 + r;   // 16-row group 0..7
#pragma unroll
            for (int kc = 0; kc < 2; ++kc) {
                load16_to_lds(A + (size_t)(m0 + f * 16 + l15) * K + k0 + kc * 32 + quad * 8,
                              sA + (f * 2 + kc) * 512);
                load16_to_lds(Bt + (size_t)(n0 + f * 16 + l15) * K + k0 + kc * 32 + quad * 8,
                              sB + (f * 2 + kc) * 512);
            }
        }
        __syncthreads();
#pragma unroll
        for (int kc = 0; kc < 2; ++kc) {
            bf16x8 af[4], bb[4];
#pragma unroll
            for (int i = 0; i < 4; ++i)
                af[i] = *(const bf16x8*)(sA + ((wr4 + i) * 2 + kc) * 512 + lane * 8);
#pragma unroll
            for (int j = 0; j < 4; ++j)
                bb[j] = *(const bf16x8*)(sB + ((wc4 + j) * 2 + kc) * 512 + lane * 8);
#pragma unroll
            for (int i = 0; i < 4; ++i)
#pragma unroll
                for (int j = 0; j < 4; ++j)
                    acc[i][j] = MFMA16(af[i], bb[j], acc[i][j]);
        }
    }
#pragma unroll
    for (int i = 0; i < 4; ++i)
#pragma unroll
        for (int j = 0; j < 4; ++j) {
            const int row = m0 + (w >> 1) * 64 + i * 16 + quad * 4;
            const int col = n0 + (w & 1) * 64 + j * 16 + l15;
#pragma unroll
            for (int r = 0; r < 4; ++r)
                store_out(C + (size_t)(row + r) * N + col, acc[i][j][r]);
        }
}

// ---------------------------------------------------------------- YaRN RoPE (in place)
// QKV [4096][3072]: Q cols 0..2047 (16 heads), K cols 2048..2559 (4 kv heads).
__global__ __launch_bounds__(256) void rope_kernel(u16* __restrict__ QKV,
                                                   const int* __restrict__ pos_ids) {
    const int idx = blockIdx.x * 256 + threadIdx.x;
    const int NQ = 4096 * 16 * 64;
    u16* p;
    int s, i;
    if (idx < NQ) {
        s = idx >> 10;
        const int hi = idx & 1023;
        const int h = hi >> 6;
        i = hi & 63;
        p = QKV + (size_t)s * 3072 + h * 128 + i;
    } else {
        const int k = idx - NQ;
        if (k >= 4096 * 4 * 64) return;
        s = k >> 8;
        const int hi = k & 255;
        const int h = hi >> 6;
        i = hi & 63;
        p = QKV + (size_t)s * 3072 + 2048 + h * 128 + i;
    }
    const float pf = (float)pos_ids[s];
    const float fi = (float)i;
    const float pos_freq = powf(500000.0f, fi * (1.0f / 64.0f));
    const float inv_ex = 1.0f / pos_freq;
    const float inv_in = inv_ex * (1.0f / 16.0f);
    const float sm = fminf(fmaxf((fi - 18.0f) * (1.0f / 17.0f), 0.0f), 1.0f);
    const float inv = (1.0f - sm) * inv_in + sm * inv_ex;
    const float ph = pf * inv;
    const float MS = 1.2772588722239781f;
    const float cs = cosf(ph) * MS, sn = sinf(ph) * MS;
    const float x1 = bf2f(p[0]), x2 = bf2f(p[64]);
    p[0] = f2bf(x1 * cs - x2 * sn);
    p[64] = f2bf(x2 * cs + x1 * sn);
}

// ---------------------------------------------------------------- V pre-transpose
// QKV [4096][3072] (V = cols 2560+kvh*128+d) -> Vt [kvh][128][4096] bf16
__global__ __launch_bounds__(256) void transpose_v(const u16* __restrict__ QKV,
                                                   u16* __restrict__ Vt) {
    __shared__ u16 tile[64 * 72];
    const int t = threadIdx.x;
    const int k0 = blockIdx.x * 64, d0 = blockIdx.y * 64, kvh = blockIdx.z;
#pragma unroll
    for (int k = 0; k < 4; ++k) {
        const int u = t + k * 256;
        const int key = u >> 4, dg = u & 15;
        const uint2 v = *(const uint2*)(QKV + (size_t)(k0 + key) * 3072 + 2560 + kvh * 128 + d0 + dg * 4);
        *(uint2*)(tile + key * 72 + dg * 4) = v;
    }
    __syncthreads();
#pragma unroll
    for (int k = 0; k < 4; ++k) {
        const int u = t + k * 256;
        const int d = u >> 4, kg = u & 15;
        union { u16 s[4]; uint2 v; } pk;
#pragma unroll
        for (int i = 0; i < 4; ++i) pk.s[i] = tile[(kg * 4 + i) * 72 + d];
        *(uint2*)(Vt + (size_t)(kvh * 128 + d0 + d) * 4096 + k0 + kg * 4) = pk.v;
    }
}

// ---------------------------------------------------------------- attention partials
// grid 1280 (bid = u*16 + h; 80 units/head, longest-first). Block: 128 q rows x one
// 1024-chunk. Wave w owns q-cols [w*32, w*32+32): S^T = K*Q^T with B=Q in regs
// (af[2][4]), 16 K-frag reads -> 32 MFMA; O^T = V^T*P^T, 16 V-frag reads -> 32 MFMA.
// (256,2): 256-reg/wave budget — R4's (256,3) spilled ~65 f32/thread to scratch.
__global__ __launch_bounds__(256, 2) void attn_partial(const u16* __restrict__ QKV,
                                                       const u16* __restrict__ Vt,
                                                       u16* __restrict__ part,
                                                       float* __restrict__ ml) {
    __shared__ __align__(16) u16 sK[8192];   // 16 KB: K frags (Q staging frags 0..15)
    __shared__ __align__(16) u16 sV[8192];   // 16 KB: V^T frags (Q staging frags 16..31)
    __shared__ __align__(16) u16 sP[8192];   // 16 KB: per-wave P^T B-frags (4 x 4KB)

    const int t = threadIdx.x;
    const int lane = t & 63, w = t >> 6;
    const int quad = lane >> 4, l15 = lane & 15;
    const int bid = blockIdx.x;
    const int u = bid >> 4, h = bid & 15, kvh = h >> 2;

    // unit decode (longest-first): u<48 full chunks, u>=48 diagonal by desc length
    int qb, c;
    if (u < 8)       { qb = 8 + u; c = 0; }
    else if (u < 24) { const int r = u - 8;  qb = 16 + (r >> 1); c = r & 1; }
    else if (u < 48) { const int r = u - 24; const int q3 = r / 3; qb = 24 + q3; c = r - q3 * 3; }
    else             { const int r = u - 48; const int k = r >> 2; const int g0 = r & 3;
                       qb = g0 * 8 + (7 - k); c = g0; }
    const int g = qb >> 3;
    const int q0 = qb << 7, kv0 = c << 10;
    const int jmax = (c == g) ? (2 * (qb & 7) + 2) : 16;

    // stage Q into 32 frags across sK+sV, then into registers af[qg][kc]
    {
        u16* dst0 = (w < 2) ? (u16*)sK : (u16*)sV;
        const int fbase = (w & 1) * 8;
#pragma unroll
        for (int idx = 0; idx < 8; ++idx) {
            const int qg = idx >> 2, kc = idx & 3;
            load16_to_lds(QKV + (size_t)(q0 + w * 32 + qg * 16 + l15) * 3072 + h * 128 + kc * 32 + quad * 8,
                          dst0 + (fbase + idx) * 512);
        }
    }
    __syncthreads();
    bf16x8 af[2][4];
    {
        const u16* src0 = (w < 2) ? (const u16*)sK : (const u16*)sV;
        const int fbase = (w & 1) * 8;
#pragma unroll
        for (int qg = 0; qg < 2; ++qg)
#pragma unroll
            for (int kc = 0; kc < 4; ++kc)
                af[qg][kc] = *(const bf16x8*)(src0 + (fbase + qg * 4 + kc) * 512 + lane * 8);
    }

    float m_c[2] = {-1e30f, -1e30f}, l_c[2] = {0.0f, 0.0f};
    f32x4 o_c[8][2] = {};
    const float SCALE = 0.08838834764831845f;  // 128^-0.5

    for (int j = 0; j < jmax; ++j) {
        const int kt0 = kv0 + (j << 6);
        __syncthreads();   // prior tile consumed (Q-frag reads on first iter)
        // stage K: wave w -> frags (kg=w, kc=0..3); V^T: frags (dt=w*2+(r>>1), ks=r&1)
        {
            const u16* gk = QKV + (size_t)(kt0 + w * 16 + l15) * 3072 + 2048 + kvh * 128 + quad * 8;
#pragma unroll
            for (int kc = 0; kc < 4; ++kc)
                load16_to_lds(gk + kc * 32, sK + (w * 4 + kc) * 512);
#pragma unroll
            for (int r = 0; r < 4; ++r) {
                const int dt = w * 2 + (r >> 1), ks = r & 1;
                load16_to_lds(Vt + (size_t)(kvh * 128 + dt * 16 + l15) * 4096 + kt0 + ks * 32 + quad * 8,
                              sV + (dt * 2 + ks) * 512);
            }
        }
        __syncthreads();

        // S^T = K * Q^T : 16 K-frag reads, 32 MFMA (reuse across qg)
        f32x4 sacc[4][2] = {};
#pragma unroll
        for (int j4 = 0; j4 < 4; ++j4)
#pragma unroll
            for (int kc = 0; kc < 4; ++kc) {
                const bf16x8 kf = *(const bf16x8*)(sK + (j4 * 4 + kc) * 512 + lane * 8);
                sacc[j4][0] = MFMA16(kf, af[0][kc], sacc[j4][0]);
                sacc[j4][1] = MFMA16(kf, af[1][kc], sacc[j4][1]);
            }

        // scale + causal mask (only last two tiles of diagonal chunk)
        const bool diag = (c == g) && ((j >> 1) == (qb & 7));
        if (diag) {
#pragma unroll
            for (int j4 = 0; j4 < 4; ++j4)
#pragma unroll
                for (int qg = 0; qg < 2; ++qg) {
                    const int qrow = q0 + w * 32 + qg * 16 + l15;
#pragma unroll
                    for (int r = 0; r < 4; ++r) {
                        const int key = kt0 + j4 * 16 + quad * 4 + r;
                        sacc[j4][qg][r] = (key > qrow) ? -1e30f : sacc[j4][qg][r] * SCALE;
                    }
                }
        } else {
#pragma unroll
            for (int j4 = 0; j4 < 4; ++j4)
#pragma unroll
                for (int qg = 0; qg < 2; ++qg)
#pragma unroll
                    for (int r = 0; r < 4; ++r)
                        sacc[j4][qg][r] *= SCALE;
        }

        // online softmax per qg (qrow = l15 lane state; reduce across quads)
#pragma unroll
        for (int qg = 0; qg < 2; ++qg) {
            float mx = -1e30f;
#pragma unroll
            for (int j4 = 0; j4 < 4; ++j4)
#pragma unroll
                for (int r = 0; r < 4; ++r) mx = fmaxf(mx, sacc[j4][qg][r]);
            mx = fmaxf(mx, __shfl_xor(mx, 16, 64));
            mx = fmaxf(mx, __shfl_xor(mx, 32, 64));
            const float mn = fmaxf(m_c[qg], mx);
            const float alpha = __expf(m_c[qg] - mn);
            float ps = 0.0f;
#pragma unroll
            for (int j4 = 0; j4 < 4; ++j4)
#pragma unroll
                for (int r = 0; r < 4; ++r) {
                    const float pe = __expf(sacc[j4][qg][r] - mn);
                    sacc[j4][qg][r] = pe;
                    ps += pe;
                }
            ps += __shfl_xor(ps, 16, 64);
            ps += __shfl_xor(ps, 32, 64);
            l_c[qg] = l_c[qg] * alpha + ps;
            m_c[qg] = mn;
#pragma unroll
            for (int dt = 0; dt < 8; ++dt) o_c[dt][qg] *= alpha;
        }

        // pack P^T into per-wave B-frags: frag (qg*2+ks), written as u32 pairs
#pragma unroll
        for (int ks = 0; ks < 2; ++ks)
#pragma unroll
            for (int jj = 0; jj < 2; ++jj) {
                const int j4 = ks * 2 + jj;
                const int quadp = jj * 2 + (quad >> 1);
#pragma unroll
                for (int qg = 0; qg < 2; ++qg)
#pragma unroll
                    for (int pr = 0; pr < 2; ++pr) {
                        const int r = pr * 2;
                        const int jje = (quad & 1) * 4 + r;
                        const u32 pk = ((u32)f2bf(sacc[j4][qg][r + 1]) << 16) | f2bf(sacc[j4][qg][r]);
                        *(u32*)(sP + w * 2048 + (qg * 2 + ks) * 512 + (quadp * 16 + l15) * 8 + jje) = pk;
                    }
            }

        // O^T += V^T * P^T : 16 V-frag reads, 32 MFMA (reuse across qg)
#pragma unroll
        for (int ks = 0; ks < 2; ++ks) {
            const bf16x8 pf0 = *(const bf16x8*)(sP + w * 2048 + (0 * 2 + ks) * 512 + lane * 8);
            const bf16x8 pf1 = *(const bf16x8*)(sP + w * 2048 + (1 * 2 + ks) * 512 + lane * 8);
#pragma unroll
            for (int dt = 0; dt < 8; ++dt) {
                const bf16x8 vf = *(const bf16x8*)(sV + (dt * 2 + ks) * 512 + lane * 8);
                o_c[dt][0] = MFMA16(vf, pf0, o_c[dt][0]);
                o_c[dt][1] = MFMA16(vf, pf1, o_c[dt][1]);
            }
        }
    }

    // epilogue: part [bid][d=128][q=128] fp16, ml [bid][q=128][2] fp32
#pragma unroll
    for (int qg = 0; qg < 2; ++qg) {
        const float invl = 1.0f / l_c[qg];
        const int q = w * 32 + qg * 16 + l15;
#pragma unroll
        for (int dt = 0; dt < 8; ++dt)
#pragma unroll
            for (int r = 0; r < 4; ++r)
                part[(size_t)bid * 16384 + (dt * 16 + quad * 4 + r) * 128 + q] =
                    f2h(o_c[dt][qg][r] * invl);
        if (quad == 0) {
            ml[(size_t)bid * 256 + q * 2] = m_c[qg];
            ml[(size_t)bid * 256 + q * 2 + 1] = l_c[qg];
        }
    }
}

// ---------------------------------------------------------------- merge partials
// grid (512, 2): x = qb*16+h, y = d-half. Thread: qrow = t&127, dgrp = t>>7 -> 32 d.
// Reference merge IN CHUNK ORDER: d = a + sE + 1e-10; o = o*(l_g/d) + ohat*sE/d.
__global__ __launch_bounds__(256) void attn_merge(const u16* __restrict__ part,
                                                  const float* __restrict__ ml,
                                                  u16* __restrict__ attn) {
    const int b = blockIdx.x;
    const int qb = b >> 4, h = b & 15;
    const int g = qb >> 3;
    const int t = threadIdx.x;
    const int qrow = t & 127;
    const int d0 = blockIdx.y * 64 + (t >> 7) * 32;

    float o[32];
#pragma unroll
    for (int i = 0; i < 32; ++i) o[i] = 0.0f;
    float m_g = -1e30f, l_g = 0.0f;

    for (int c = 0; c <= g; ++c) {
        int u;
        if (c == g)      u = 48 + (7 - (qb & 7)) * 4 + g;
        else if (g == 1) u = qb - 8;
        else if (g == 2) u = 8 + (qb - 16) * 2 + c;
        else             u = 24 + (qb - 24) * 3 + c;
        const int tile = u * 16 + h;
        const float m_c = ml[(size_t)tile * 256 + qrow * 2];
        const float l_c = ml[(size_t)tile * 256 + qrow * 2 + 1];
        const float mn = fmaxf(m_g, m_c);
        const float a = l_g * __expf(m_g - mn);
        const float eC = __expf(m_c - mn);
        const float sE = l_c * eC;
        const float d = a + sE + 1e-10f;
        const float f_old = l_g / d;
        const float f_new = sE / d;
#pragma unroll
        for (int i = 0; i < 32; ++i) {
            const float v = h2f(part[(size_t)tile * 16384 + (d0 + i) * 128 + qrow]);
            o[i] = o[i] * f_old + v * f_new;
        }
        l_g = a + sE;
        m_g = mn;
    }

    u16* dst = attn + (size_t)(qb * 128 + qrow) * 2048 + h * 128 + d0;
#pragma unroll
    for (int kq = 0; kq < 4; ++kq) {
        union { u16 s[8]; uint4 v; } pk;
#pragma unroll
        for (int i = 0; i < 8; ++i) pk.s[i] = f2bf(o[kq * 8 + i]);
        *(uint4*)(dst + kq * 8) = pk.v;
    }
}

// ---------------------------------------------------------------- launch
extern "C" void kernel_launch(void* const* d_in, const int* in_sizes, int n_in,
                              void* d_out, int out_size, void* d_ws, size_t ws_size,
                              hipStream_t stream) {
    const float* X  = (const float*)d_in[0];
    const int* pos  = (const int*)d_in[1];
    const float* Wq = (const float*)d_in[2];
    const float* Wk = (const float*)d_in[3];
    const float* Wv = (const float*)d_in[4];
    const float* Wo = (const float*)d_in[5];
    float* out = (float*)d_out;
    char* ws = (char*)d_ws;

    u16*   part = (u16*)(ws);
    u16*   Xbf  = (u16*)(ws);                      // overlay (dead before part)
    u16*   Wt   = (u16*)(ws + 16777216);           // [3072][2048] overlay
    u16*   QKV  = (u16*)(ws + 41943040);
    u16*   attn = (u16*)(ws + 41943040);           // overlay QKV (dead after partials)
    u16*   Vt   = (u16*)(ws + 67108864);
    float* ml   = (float*)(ws + 71303168);
    u16*   Wot  = (u16*)(ws + 72613888);

    convert_f32_bf16<<<8192, 256, 0, stream>>>(X, Xbf);
    transpose_w<<<dim3(32, 32), 256, 0, stream>>>(Wq, Wt, 2048);
    transpose_w<<<dim3(8, 32), 256, 0, stream>>>(Wk, Wt + (size_t)2048 * 2048, 512);
    transpose_w<<<dim3(8, 32), 256, 0, stream>>>(Wv, Wt + (size_t)2560 * 2048, 512);
    transpose_w<<<dim3(32, 32), 256, 0, stream>>>(Wo, Wot, 2048);

    gemm_bt<u16><<<dim3(32, 24), 256, 0, stream>>>(Xbf, Wt, QKV, 4096, 3072, 2048);

    rope_kernel<<<20480, 256, 0, stream>>>(QKV, pos);
    transpose_v<<<dim3(64, 2, 4), 256, 0, stream>>>(QKV, Vt);

    attn_partial<<<1280, 256, 0, stream>>>(QKV, Vt, part, ml);
    attn_merge<<<dim3(512, 2), 256, 0, stream>>>(part, ml, attn);

    gemm_bt<float><<<dim3(32, 16), 256, 0, stream>>>(attn, Wot, out, 4096, 2048, 2048);
}

// Round 6
// 450.813 us; speedup vs baseline: 1.1201x; 1.0187x over previous
//
#include <hip/hip_runtime.h>
#include <cstdint>
#include <cstddef>

// B=1, S=4096, HIDDEN=2048, HEADS=16, KVH=4, HD=128, CHUNK=1024.
// R6: attn_partial gets single-barrier double-buffered K/V prefetch (glds for
// tile j+1 issued before compute of tile j; one barrier per iter, was two —
// hides the ~500-900 cyc load latency that R5 exposed every iteration).
// Launch count 11 -> 7 (transpose_w x4 fused; transpose_v folded into rope).
//
// ws arena (bytes), liveness overlays:
//   part  @ 0          41,943,040   (overlays Xbf@0 16MB + Wt@16MB 12.6MB)
//   QKV   @ 41,943,040 25,165,824   ([4096][3072]: Q | K | V bf16)
//     attn @ 41,943,040 16,777,216  (overlay after partials done)
//   Vt    @ 67,108,864  4,194,304   ([kvh][128][4096] bf16)
//   ml    @ 71,303,168  1,310,720   (fp32 m,l per q-row per partial)
//   Wot   @ 72,613,888  8,388,608
//   total 81,002,496 (~77.3 MB)

typedef unsigned short u16;
typedef unsigned int u32;
typedef float f32x4 __attribute__((ext_vector_type(4)));
typedef __bf16 bf16x8 __attribute__((ext_vector_type(8)));

__device__ __forceinline__ u16 f2bf(float f) {
    union { float f; u32 u; } v; v.f = f;
    u32 u = v.u;
    u += 0x7fffu + ((u >> 16) & 1u);
    return (u16)(u >> 16);
}
__device__ __forceinline__ float bf2f(u16 b) {
    union { u32 u; float f; } v; v.u = ((u32)b) << 16;
    return v.f;
}
__device__ __forceinline__ u16 f2h(float f) {
    union { _Float16 h; u16 u; } v; v.h = (_Float16)f; return v.u;
}
__device__ __forceinline__ float h2f(u16 u) {
    union { u16 u; _Float16 h; } v; v.u = u; return (float)v.h;
}

__device__ __forceinline__ void load16_to_lds(const void* g, void* l) {
    __builtin_amdgcn_global_load_lds((const __attribute__((address_space(1))) u32*)g,
                                     (__attribute__((address_space(3))) u32*)l,
                                     16, 0, 0);
}

#define MFMA16(a, b, c) __builtin_amdgcn_mfma_f32_16x16x32_bf16((a), (b), (c), 0, 0, 0)

// ---------------------------------------------------------------- convert X
__global__ __launch_bounds__(256) void convert_f32_bf16(const float* __restrict__ X,
                                                        u16* __restrict__ Y) {
    const int base = (blockIdx.x * 1024 + threadIdx.x) * 4;
#pragma unroll
    for (int k = 0; k < 4; ++k) {
        const int i = base + k * 1024;
        const float4 v = *(const float4*)(X + i);
        union { u16 s[4]; uint2 u; } pk;
        pk.s[0] = f2bf(v.x); pk.s[1] = f2bf(v.y); pk.s[2] = f2bf(v.z); pk.s[3] = f2bf(v.w);
        *(uint2*)(Y + i) = pk.u;
    }
}

// -------------------------- fused transpose of all 4 weights -> bf16 [N][K]
// grid (80, 32): x<32 Wq->Wt, x<40 Wk->Wt+2048*2048, x<48 Wv->Wt+2560*2048,
// x>=48 Wo->Wot. Source is [K=2048][N] fp32.
__global__ __launch_bounds__(256) void transpose_w4(const float* __restrict__ Wq,
                                                    const float* __restrict__ Wk,
                                                    const float* __restrict__ Wv,
                                                    const float* __restrict__ Wo,
                                                    u16* __restrict__ Wt,
                                                    u16* __restrict__ Wot) {
    __shared__ float tile[64][65];
    const int bx = blockIdx.x;
    const float* W; u16* dst; int N, n0;
    if (bx < 32)      { W = Wq; dst = Wt;                          N = 2048; n0 = bx * 64; }
    else if (bx < 40) { W = Wk; dst = Wt + (size_t)2048 * 2048;    N = 512;  n0 = (bx - 32) * 64; }
    else if (bx < 48) { W = Wv; dst = Wt + (size_t)2560 * 2048;    N = 512;  n0 = (bx - 40) * 64; }
    else              { W = Wo; dst = Wot;                         N = 2048; n0 = (bx - 48) * 64; }
    const int k0 = blockIdx.y * 64;
    const int tc = threadIdx.x & 63, tr = threadIdx.x >> 6;
#pragma unroll
    for (int i = 0; i < 64; i += 4)
        tile[tc][tr + i] = W[(size_t)(k0 + tr + i) * N + n0 + tc];
    __syncthreads();
#pragma unroll
    for (int i = 0; i < 64; i += 4)
        dst[(size_t)(n0 + tr + i) * 2048 + k0 + tc] = f2bf(tile[tr + i][tc]);
}

// ---------------------------------------------------------------- GEMM C = A * Bt^T
// BK=64: 16 frags x 1KB per matrix (32 KB LDS), 32 MFMA per barrier pair.
// Frag-ordered LDS -> conflict-free ds_read_b128; glds width-16 staging.
__device__ __forceinline__ void store_out(float* p, float v) { *p = v; }
__device__ __forceinline__ void store_out(u16* p, float v) { *p = f2bf(v); }

template <typename OutT>
__global__ __launch_bounds__(256) void gemm_bt(const u16* __restrict__ A,
                                               const u16* __restrict__ Bt,
                                               OutT* __restrict__ C,
                                               int M, int N, int K) {
    __shared__ __align__(16) u16 sA[8192];
    __shared__ __align__(16) u16 sB[8192];
    const int t = threadIdx.x;
    const int lane = t & 63, w = t >> 6;
    const int quad = lane >> 4, l15 = lane & 15;
    const int m0 = blockIdx.x << 7, n0 = blockIdx.y << 7;
    const int wr4 = (w >> 1) * 4, wc4 = (w & 1) * 4;
    f32x4 acc[4][4] = {};
    for (int k0 = 0; k0 < K; k0 += 64) {
        __syncthreads();
#pragma unroll
        for (int r = 0; r < 2; ++r) {
            const int f = w * 2 + r;
#pragma unroll
            for (int kc = 0; kc < 2; ++kc) {
                load16_to_lds(A + (size_t)(m0 + f * 16 + l15) * K + k0 + kc * 32 + quad * 8,
                              sA + (f * 2 + kc) * 512);
                load16_to_lds(Bt + (size_t)(n0 + f * 16 + l15) * K + k0 + kc * 32 + quad * 8,
                              sB + (f * 2 + kc) * 512);
            }
        }
        __syncthreads();
#pragma unroll
        for (int kc = 0; kc < 2; ++kc) {
            bf16x8 af[4], bb[4];
#pragma unroll
            for (int i = 0; i < 4; ++i)
                af[i] = *(const bf16x8*)(sA + ((wr4 + i) * 2 + kc) * 512 + lane * 8);
#pragma unroll
            for (int j = 0; j < 4; ++j)
                bb[j] = *(const bf16x8*)(sB + ((wc4 + j) * 2 + kc) * 512 + lane * 8);
#pragma unroll
            for (int i = 0; i < 4; ++i)
#pragma unroll
                for (int j = 0; j < 4; ++j)
                    acc[i][j] = MFMA16(af[i], bb[j], acc[i][j]);
        }
    }
#pragma unroll
    for (int i = 0; i < 4; ++i)
#pragma unroll
        for (int j = 0; j < 4; ++j) {
            const int row = m0 + (w >> 1) * 64 + i * 16 + quad * 4;
            const int col = n0 + (w & 1) * 64 + j * 16 + l15;
#pragma unroll
            for (int r = 0; r < 4; ++r)
                store_out(C + (size_t)(row + r) * N + col, acc[i][j][r]);
        }
}

// --------------------------------------- fused YaRN RoPE (in place) + V transpose
// blocks 0..20479: rope on QKV (Q cols 0..2047, K cols 2048..2559).
// blocks 20480..20991: transpose V (cols 2560+) -> Vt [kvh][128][4096].
__global__ __launch_bounds__(256) void rope_vt_kernel(u16* __restrict__ QKV,
                                                      u16* __restrict__ Vt,
                                                      const int* __restrict__ pos_ids) {
    __shared__ u16 tile[64 * 72];
    if (blockIdx.x >= 20480) {
        const int b = blockIdx.x - 20480;           // (64, 2, 4) linearized
        const int k0 = (b & 63) * 64, d0 = ((b >> 6) & 1) * 64, kvh = b >> 7;
        const int t = threadIdx.x;
#pragma unroll
        for (int k = 0; k < 4; ++k) {
            const int u = t + k * 256;
            const int key = u >> 4, dg = u & 15;
            const uint2 v = *(const uint2*)(QKV + (size_t)(k0 + key) * 3072 + 2560 + kvh * 128 + d0 + dg * 4);
            *(uint2*)(tile + key * 72 + dg * 4) = v;
        }
        __syncthreads();
#pragma unroll
        for (int k = 0; k < 4; ++k) {
            const int u = t + k * 256;
            const int d = u >> 4, kg = u & 15;
            union { u16 s[4]; uint2 v; } pk;
#pragma unroll
            for (int i = 0; i < 4; ++i) pk.s[i] = tile[(kg * 4 + i) * 72 + d];
            *(uint2*)(Vt + (size_t)(kvh * 128 + d0 + d) * 4096 + k0 + kg * 4) = pk.v;
        }
        return;
    }
    const int idx = blockIdx.x * 256 + threadIdx.x;
    const int NQ = 4096 * 16 * 64;
    u16* p;
    int s, i;
    if (idx < NQ) {
        s = idx >> 10;
        const int hi = idx & 1023;
        const int h = hi >> 6;
        i = hi & 63;
        p = QKV + (size_t)s * 3072 + h * 128 + i;
    } else {
        const int k = idx - NQ;
        s = k >> 8;
        const int hi = k & 255;
        const int h = hi >> 6;
        i = hi & 63;
        p = QKV + (size_t)s * 3072 + 2048 + h * 128 + i;
    }
    const float pf = (float)pos_ids[s];
    const float fi = (float)i;
    const float pos_freq = powf(500000.0f, fi * (1.0f / 64.0f));
    const float inv_ex = 1.0f / pos_freq;
    const float inv_in = inv_ex * (1.0f / 16.0f);
    const float sm = fminf(fmaxf((fi - 18.0f) * (1.0f / 17.0f), 0.0f), 1.0f);
    const float inv = (1.0f - sm) * inv_in + sm * inv_ex;
    const float ph = pf * inv;
    const float MS = 1.2772588722239781f;
    const float cs = cosf(ph) * MS, sn = sinf(ph) * MS;
    const float x1 = bf2f(p[0]), x2 = bf2f(p[64]);
    p[0] = f2bf(x1 * cs - x2 * sn);
    p[64] = f2bf(x2 * cs + x1 * sn);
}

// ---------------------------------------------------------------- attention partials
// grid 1280 (bid = u*16 + h; 80 units/head, longest-first). Block: 128 q rows x one
// 1024-chunk. Wave w owns q-cols [w*32,+32): S^T = K*Q^T (B=Q in regs, af[2][4]),
// O^T = V^T*P^T. Double-buffered K/V staging, ONE barrier per key-tile: prefetch
// glds for tile j+1 issued before compute of tile j — latency hidden under compute.
// (256,2): 256-reg/wave budget (R4's (256,3) spilled).
__device__ __forceinline__ void stage_kv(const u16* __restrict__ QKV,
                                         const u16* __restrict__ Vt,
                                         int kt0, int kvh, int w, int l15, int quad,
                                         u16* bK, u16* bV) {
    const u16* gk = QKV + (size_t)(kt0 + w * 16 + l15) * 3072 + 2048 + kvh * 128 + quad * 8;
#pragma unroll
    for (int kc = 0; kc < 4; ++kc)
        load16_to_lds(gk + kc * 32, bK + (w * 4 + kc) * 512);
#pragma unroll
    for (int r = 0; r < 4; ++r) {
        const int dt = w * 2 + (r >> 1), ks = r & 1;
        load16_to_lds(Vt + (size_t)(kvh * 128 + dt * 16 + l15) * 4096 + kt0 + ks * 32 + quad * 8,
                      bV + (dt * 2 + ks) * 512);
    }
}

__global__ __launch_bounds__(256, 2) void attn_partial(const u16* __restrict__ QKV,
                                                       const u16* __restrict__ Vt,
                                                       u16* __restrict__ part,
                                                       float* __restrict__ ml) {
    __shared__ __align__(16) u16 sK[2][8192];   // 2 x 16 KB ping-pong K frags
    __shared__ __align__(16) u16 sV[2][8192];   // 2 x 16 KB ping-pong V^T frags
    __shared__ __align__(16) u16 sP[8192];      // 16 KB per-wave P^T B-frags

    const int t = threadIdx.x;
    const int lane = t & 63, w = t >> 6;
    const int quad = lane >> 4, l15 = lane & 15;
    const int bid = blockIdx.x;
    const int u = bid >> 4, h = bid & 15, kvh = h >> 2;

    // unit decode (longest-first): u<48 full chunks, u>=48 diagonal by desc length
    int qb, c;
    if (u < 8)       { qb = 8 + u; c = 0; }
    else if (u < 24) { const int r = u - 8;  qb = 16 + (r >> 1); c = r & 1; }
    else if (u < 48) { const int r = u - 24; const int q3 = r / 3; qb = 24 + q3; c = r - q3 * 3; }
    else             { const int r = u - 48; const int k = r >> 2; const int g0 = r & 3;
                       qb = g0 * 8 + (7 - k); c = g0; }
    const int g = qb >> 3;
    const int q0 = qb << 7, kv0 = c << 10;
    const int jmax = (c == g) ? (2 * (qb & 7) + 2) : 16;

    // stage Q into 32 frags across sK[0]+sK[1], then into registers af[qg][kc]
    {
        u16* dst0 = (w < 2) ? sK[0] : sK[1];
        const int fbase = (w & 1) * 8;
#pragma unroll
        for (int idx = 0; idx < 8; ++idx) {
            const int qg = idx >> 2, kc = idx & 3;
            load16_to_lds(QKV + (size_t)(q0 + w * 32 + qg * 16 + l15) * 3072 + h * 128 + kc * 32 + quad * 8,
                          dst0 + (fbase + idx) * 512);
        }
    }
    __syncthreads();
    bf16x8 af[2][4];
    {
        const u16* src0 = (w < 2) ? sK[0] : sK[1];
        const int fbase = (w & 1) * 8;
#pragma unroll
        for (int qg = 0; qg < 2; ++qg)
#pragma unroll
            for (int kc = 0; kc < 4; ++kc)
                af[qg][kc] = *(const bf16x8*)(src0 + (fbase + qg * 4 + kc) * 512 + lane * 8);
    }
    __syncthreads();   // Q reads complete before tile-0 staging overwrites sK[0]

    stage_kv(QKV, Vt, kv0, kvh, w, l15, quad, sK[0], sV[0]);   // prefetch tile 0

    float m_c[2] = {-1e30f, -1e30f}, l_c[2] = {0.0f, 0.0f};
    f32x4 o_c[8][2] = {};
    const float SCALE = 0.08838834764831845f;  // 128^-0.5

    for (int j = 0; j < jmax; ++j) {
        const int kt0 = kv0 + (j << 6);
        const int p = j & 1;
        __syncthreads();   // drains glds tile j (issued ~1 compute-phase ago); guards buf reuse
        if (j + 1 < jmax)
            stage_kv(QKV, Vt, kv0 + ((j + 1) << 6), kvh, w, l15, quad, sK[1 - p], sV[1 - p]);

        // S^T = K * Q^T : 16 K-frag reads, 32 MFMA (reuse across qg)
        f32x4 sacc[4][2] = {};
#pragma unroll
        for (int j4 = 0; j4 < 4; ++j4)
#pragma unroll
            for (int kc = 0; kc < 4; ++kc) {
                const bf16x8 kf = *(const bf16x8*)(sK[p] + (j4 * 4 + kc) * 512 + lane * 8);
                sacc[j4][0] = MFMA16(kf, af[0][kc], sacc[j4][0]);
                sacc[j4][1] = MFMA16(kf, af[1][kc], sacc[j4][1]);
            }

        // scale + causal mask (only last two tiles of diagonal chunk)
        const bool diag = (c == g) && ((j >> 1) == (qb & 7));
        if (diag) {
#pragma unroll
            for (int j4 = 0; j4 < 4; ++j4)
#pragma unroll
                for (int qg = 0; qg < 2; ++qg) {
                    const int qrow = q0 + w * 32 + qg * 16 + l15;
#pragma unroll
                    for (int r = 0; r < 4; ++r) {
                        const int key = kt0 + j4 * 16 + quad * 4 + r;
                        sacc[j4][qg][r] = (key > qrow) ? -1e30f : sacc[j4][qg][r] * SCALE;
                    }
                }
        } else {
#pragma unroll
            for (int j4 = 0; j4 < 4; ++j4)
#pragma unroll
                for (int qg = 0; qg < 2; ++qg)
#pragma unroll
                    for (int r = 0; r < 4; ++r)
                        sacc[j4][qg][r] *= SCALE;
        }

        // online softmax per qg (qrow = l15 lane state; reduce across quads)
#pragma unroll
        for (int qg = 0; qg < 2; ++qg) {
            float mx = -1e30f;
#pragma unroll
            for (int j4 = 0; j4 < 4; ++j4)
#pragma unroll
                for (int r = 0; r < 4; ++r) mx = fmaxf(mx, sacc[j4][qg][r]);
            mx = fmaxf(mx, __shfl_xor(mx, 16, 64));
            mx = fmaxf(mx, __shfl_xor(mx, 32, 64));
            const float mn = fmaxf(m_c[qg], mx);
            const float alpha = __expf(m_c[qg] - mn);
            float ps = 0.0f;
#pragma unroll
            for (int j4 = 0; j4 < 4; ++j4)
#pragma unroll
                for (int r = 0; r < 4; ++r) {
                    const float pe = __expf(sacc[j4][qg][r] - mn);
                    sacc[j4][qg][r] = pe;
                    ps += pe;
                }
            ps += __shfl_xor(ps, 16, 64);
            ps += __shfl_xor(ps, 32, 64);
            l_c[qg] = l_c[qg] * alpha + ps;
            m_c[qg] = mn;
#pragma unroll
            for (int dt = 0; dt < 8; ++dt) o_c[dt][qg] *= alpha;
        }

        // pack P^T into per-wave B-frags: frag (qg*2+ks), written as u32 pairs
#pragma unroll
        for (int ks = 0; ks < 2; ++ks)
#pragma unroll
            for (int jj = 0; jj < 2; ++jj) {
                const int j4 = ks * 2 + jj;
                const int quadp = jj * 2 + (quad >> 1);
#pragma unroll
                for (int qg = 0; qg < 2; ++qg)
#pragma unroll
                    for (int pr = 0; pr < 2; ++pr) {
                        const int r = pr * 2;
                        const int jje = (quad & 1) * 4 + r;
                        const u32 pk = ((u32)f2bf(sacc[j4][qg][r + 1]) << 16) | f2bf(sacc[j4][qg][r]);
                        *(u32*)(sP + w * 2048 + (qg * 2 + ks) * 512 + (quadp * 16 + l15) * 8 + jje) = pk;
                    }
            }

        // O^T += V^T * P^T : 16 V-frag reads, 32 MFMA (reuse across qg)
#pragma unroll
        for (int ks = 0; ks < 2; ++ks) {
            const bf16x8 pf0 = *(const bf16x8*)(sP + w * 2048 + (0 * 2 + ks) * 512 + lane * 8);
            const bf16x8 pf1 = *(const bf16x8*)(sP + w * 2048 + (1 * 2 + ks) * 512 + lane * 8);
#pragma unroll
            for (int dt = 0; dt < 8; ++dt) {
                const bf16x8 vf = *(const bf16x8*)(sV[p] + (dt * 2 + ks) * 512 + lane * 8);
                o_c[dt][0] = MFMA16(vf, pf0, o_c[dt][0]);
                o_c[dt][1] = MFMA16(vf, pf1, o_c[dt][1]);
            }
        }
    }

    // epilogue: part [bid][d=128][q=128] fp16, ml [bid][q=128][2] fp32
#pragma unroll
    for (int qg = 0; qg < 2; ++qg) {
        const float invl = 1.0f / l_c[qg];
        const int q = w * 32 + qg * 16 + l15;
#pragma unroll
        for (int dt = 0; dt < 8; ++dt)
#pragma unroll
            for (int r = 0; r < 4; ++r)
                part[(size_t)bid * 16384 + (dt * 16 + quad * 4 + r) * 128 + q] =
                    f2h(o_c[dt][qg][r] * invl);
        if (quad == 0) {
            ml[(size_t)bid * 256 + q * 2] = m_c[qg];
            ml[(size_t)bid * 256 + q * 2 + 1] = l_c[qg];
        }
    }
}

// ---------------------------------------------------------------- merge partials
// grid (512, 2): x = qb*16+h, y = d-half. Thread: qrow = t&127, dgrp = t>>7 -> 32 d.
// Reference merge IN CHUNK ORDER: d = a + sE + 1e-10; o = o*(l_g/d) + ohat*sE/d.
__global__ __launch_bounds__(256) void attn_merge(const u16* __restrict__ part,
                                                  const float* __restrict__ ml,
                                                  u16* __restrict__ attn) {
    const int b = blockIdx.x;
    const int qb = b >> 4, h = b & 15;
    const int g = qb >> 3;
    const int t = threadIdx.x;
    const int qrow = t & 127;
    const int d0 = blockIdx.y * 64 + (t >> 7) * 32;

    float o[32];
#pragma unroll
    for (int i = 0; i < 32; ++i) o[i] = 0.0f;
    float m_g = -1e30f, l_g = 0.0f;

    for (int c = 0; c <= g; ++c) {
        int u;
        if (c == g)      u = 48 + (7 - (qb & 7)) * 4 + g;
        else if (g == 1) u = qb - 8;
        else if (g == 2) u = 8 + (qb - 16) * 2 + c;
        else             u = 24 + (qb - 24) * 3 + c;
        const int tile = u * 16 + h;
        const float m_c = ml[(size_t)tile * 256 + qrow * 2];
        const float l_c = ml[(size_t)tile * 256 + qrow * 2 + 1];
        const float mn = fmaxf(m_g, m_c);
        const float a = l_g * __expf(m_g - mn);
        const float eC = __expf(m_c - mn);
        const float sE = l_c * eC;
        const float d = a + sE + 1e-10f;
        const float f_old = l_g / d;
        const float f_new = sE / d;
#pragma unroll
        for (int i = 0; i < 32; ++i) {
            const float v = h2f(part[(size_t)tile * 16384 + (d0 + i) * 128 + qrow]);
            o[i] = o[i] * f_old + v * f_new;
        }
        l_g = a + sE;
        m_g = mn;
    }

    u16* dst = attn + (size_t)(qb * 128 + qrow) * 2048 + h * 128 + d0;
#pragma unroll
    for (int kq = 0; kq < 4; ++kq) {
        union { u16 s[8]; uint4 v; } pk;
#pragma unroll
        for (int i = 0; i < 8; ++i) pk.s[i] = f2bf(o[kq * 8 + i]);
        *(uint4*)(dst + kq * 8) = pk.v;
    }
}

// ---------------------------------------------------------------- launch
extern "C" void kernel_launch(void* const* d_in, const int* in_sizes, int n_in,
                              void* d_out, int out_size, void* d_ws, size_t ws_size,
                              hipStream_t stream) {
    const float* X  = (const float*)d_in[0];
    const int* pos  = (const int*)d_in[1];
    const float* Wq = (const float*)d_in[2];
    const float* Wk = (const float*)d_in[3];
    const float* Wv = (const float*)d_in[4];
    const float* Wo = (const float*)d_in[5];
    float* out = (float*)d_out;
    char* ws = (char*)d_ws;

    u16*   part = (u16*)(ws);
    u16*   Xbf  = (u16*)(ws);                      // overlay (dead before part)
    u16*   Wt   = (u16*)(ws + 16777216);           // [3072][2048] overlay
    u16*   QKV  = (u16*)(ws + 41943040);
    u16*   attn = (u16*)(ws + 41943040);           // overlay QKV (dead after partials)
    u16*   Vt   = (u16*)(ws + 67108864);
    float* ml   = (float*)(ws + 71303168);
    u16*   Wot  = (u16*)(ws + 72613888);

    convert_f32_bf16<<<2048, 256, 0, stream>>>(X, Xbf);
    transpose_w4<<<dim3(80, 32), 256, 0, stream>>>(Wq, Wk, Wv, Wo, Wt, Wot);

    gemm_bt<u16><<<dim3(32, 24), 256, 0, stream>>>(Xbf, Wt, QKV, 4096, 3072, 2048);

    rope_vt_kernel<<<20992, 256, 0, stream>>>(QKV, Vt, pos);

    attn_partial<<<1280, 256, 0, stream>>>(QKV, Vt, part, ml);
    attn_merge<<<dim3(512, 2), 256, 0, stream>>>(part, ml, attn);

    gemm_bt<float><<<dim3(32, 16), 256, 0, stream>>>(attn, Wot, out, 4096, 2048, 2048);
}